// Round 11
// baseline (275.727 us; speedup 1.0000x reference)
//
#include <hip/hip_runtime.h>
#include <hip/hip_bf16.h>

typedef __attribute__((ext_vector_type(4))) float f32x4;
typedef __attribute__((ext_vector_type(8))) short bf16x8;

#define LDBK 40  // shorts per Bs row (80B): b128-aligned reads, 2-way banks = free

__device__ __forceinline__ unsigned cvt2(float lo, float hi) {
    float2 t; t.x = lo; t.y = hi;
    __hip_bfloat162 h = __float22bfloat162_rn(t);   // v_cvt_pk_bf16_f32
    union { __hip_bfloat162 h; unsigned u; } c; c.h = h; return c.u;
}
__device__ __forceinline__ bf16x8 cvt8(f32x4 lo, f32x4 hi) {
    union { bf16x8 v; unsigned u[4]; } r;
    r.u[0] = cvt2(lo[0], lo[1]); r.u[1] = cvt2(lo[2], lo[3]);
    r.u[2] = cvt2(hi[0], hi[1]); r.u[3] = cvt2(hi[2], hi[3]);
    return r.v;
}

// M=64, K-step=32, 4 waves. A: global->VGPR (nt). B: 5.1KB single LDS buffer,
// depth-2 reg prefetch, raw barriers. Tiny LDS -> more independent blocks/CU
// (the duty-cycle experiment). XCD-grouped B panels.
__global__ __launch_bounds__(256, 4) void bmm2_k(const float* __restrict__ a,
                                                 const float* __restrict__ b,
                                                 float* __restrict__ out) {
    // Desc-sorted static ragged tables (M=64: s/4 blocks per seq).
    const int  cumblk[9] = {0,512,896,1216,1472,1696,1888,2048,2176};
    const int  slen[8]   = {2048,1536,1280,1024,896,768,640,512};
    const long aoff[8]   = {20971520,88080384,135266304,4194304,161480704,125829120,174325760,0};
    const int  toff[8]   = {1536,3584,5888,512,7168,5120,8064,0};

    __shared__ unsigned short Bs[64 * LDBK];   // [col j][k=32(+8)] bf16, 5.1 KB

    // Bijective XCD swizzle (2176 = 8*272): XCD x gets work-ids x*272..x*272+271.
    int bid = (blockIdx.x & 7) * 272 + (blockIdx.x >> 3);

    int i = 0;
    #pragma unroll
    for (int t = 0; t < 7; ++t) if (bid >= cumblk[t + 1]) i = t + 1;
    int rem  = bid - cumblk[i];
    int s    = slen[i];
    int nmb  = s >> 6;
    int head = rem / nmb;
    int mb   = rem - head * nmb;

    const float* A  = a + aoff[i] + (long)head * s * s + (long)mb * 64 * s;
    const float* Bp = b + (long)toff[i] * 1024 + head * 64;
    float*       Cp = out + (long)(toff[i] + mb * 64) * 1024 + head * 64;

    int tid = threadIdx.x, lane = tid & 63, wave = tid >> 6;
    int lrow = lane & 15, lgrp = lane >> 4;

    // A fragments: wave owns rows wave*16..+15; lane -> row lrow, k = lgrp*8..+7.
    const float* ar = A + (long)(wave * 16 + lrow) * s + lgrp * 8;

    // B staging (K=32 window): thread -> tokens tok0..tok0+1, cols bc..bc+3.
    int bc = (tid & 15) * 4, tok0 = (tid >> 4) * 2;   // tok0 in 0..30
    const float* Bst = Bp + (long)tok0 * 1024 + bc;

    f32x4 aC0, aC1, aN0, aN1;       // A depth-1 (consumed next phase)
    f32x4 lB0[2], lB1[2];           // B depth-2 (two static sets, 2 tokens each)
    f32x4 acc[4] = {};

    int NP = s >> 5;                // phases of K=32; always even

    // prologue
    aC0 = __builtin_nontemporal_load((const f32x4*)(ar));
    aC1 = __builtin_nontemporal_load((const f32x4*)(ar + 4));
    #pragma unroll
    for (int q = 0; q < 2; ++q) {
        lB0[q] = *(const f32x4*)(Bst + (long)q * 1024);
        lB1[q] = *(const f32x4*)(Bst + (long)(32 + q) * 1024);
    }

    for (int p = 0; p < NP; p += 2) {
        // ---- even phase: stage lB0 -> Bs, compute with aC, prefetch lB0(p+2), A(p+1) ----
        {
            __builtin_amdgcn_s_barrier();   // reads of Bs (phase p-1) done
            #pragma unroll
            for (int e = 0; e < 4; ++e)
                *(unsigned*)&Bs[(bc + e) * LDBK + tok0] = cvt2(lB0[0][e], lB0[1][e]);
            long kr = (p + 2 < NP) ? (((long)p + 2) << 5) : 0;
            #pragma unroll
            for (int q = 0; q < 2; ++q)
                lB0[q] = *(const f32x4*)(Bst + (kr + q) * 1024);
            long ka = ((long)p + 1) << 5;   // p+1 < NP always (NP even, p even)
            aN0 = __builtin_nontemporal_load((const f32x4*)(ar + ka));
            aN1 = __builtin_nontemporal_load((const f32x4*)(ar + ka + 4));
            asm volatile("s_waitcnt lgkmcnt(0)" ::: "memory");
            __builtin_amdgcn_sched_barrier(0);
            __builtin_amdgcn_s_barrier();   // Bs(p) visible
            bf16x8 af = cvt8(aC0, aC1);
            #pragma unroll
            for (int n = 0; n < 4; ++n) {
                bf16x8 bf = *(const bf16x8*)&Bs[(n * 16 + lrow) * LDBK + lgrp * 8];
                acc[n] = __builtin_amdgcn_mfma_f32_16x16x32_bf16(af, bf, acc[n], 0, 0, 0);
            }
        }
        // ---- odd phase: stage lB1 -> Bs, compute with aN, prefetch lB1(p+3), A(p+2) ----
        {
            __builtin_amdgcn_s_barrier();
            #pragma unroll
            for (int e = 0; e < 4; ++e)
                *(unsigned*)&Bs[(bc + e) * LDBK + tok0] = cvt2(lB1[0][e], lB1[1][e]);
            long kr = (p + 3 < NP) ? (((long)p + 3) << 5) : 0;
            #pragma unroll
            for (int q = 0; q < 2; ++q)
                lB1[q] = *(const f32x4*)(Bst + (kr + q) * 1024);
            long ka = (p + 2 < NP) ? (((long)p + 2) << 5) : 0;
            aC0 = __builtin_nontemporal_load((const f32x4*)(ar + ka));
            aC1 = __builtin_nontemporal_load((const f32x4*)(ar + ka + 4));
            asm volatile("s_waitcnt lgkmcnt(0)" ::: "memory");
            __builtin_amdgcn_sched_barrier(0);
            __builtin_amdgcn_s_barrier();
            bf16x8 af = cvt8(aN0, aN1);
            #pragma unroll
            for (int n = 0; n < 4; ++n) {
                bf16x8 bf = *(const bf16x8*)&Bs[(n * 16 + lrow) * LDBK + lgrp * 8];
                acc[n] = __builtin_amdgcn_mfma_f32_16x16x32_bf16(af, bf, acc[n], 0, 0, 0);
            }
        }
    }

    // epilogue: C/D layout col=lane&15, row=4*(lane>>4)+reg (verified R1); NT stores
    #pragma unroll
    for (int n = 0; n < 4; ++n)
        #pragma unroll
        for (int r = 0; r < 4; ++r) {
            int q = wave * 16 + lgrp * 4 + r;
            __builtin_nontemporal_store(acc[n][r], &Cp[(long)q * 1024 + n * 16 + lrow]);
        }
}

extern "C" void kernel_launch(void* const* d_in, const int* in_sizes, int n_in,
                              void* d_out, int out_size, void* d_ws, size_t ws_size,
                              hipStream_t stream) {
    const float* a = (const float*)d_in[0];
    const float* b = (const float*)d_in[1];
    float* out = (float*)d_out;
    bmm2_k<<<2176, 256, 0, stream>>>(a, b, out);
}

// Round 12
// 192.787 us; speedup vs baseline: 1.4302x; 1.4302x over previous
//
#include <hip/hip_runtime.h>
#include <hip/hip_bf16.h>

typedef __attribute__((ext_vector_type(4))) float f32x4;
typedef __attribute__((ext_vector_type(8))) short bf16x8;
typedef __attribute__((ext_vector_type(4))) short bf16x4;

__device__ __forceinline__ unsigned cvt2(float lo, float hi) {
    float2 t; t.x = lo; t.y = hi;
    __hip_bfloat162 h = __float22bfloat162_rn(t);   // v_cvt_pk_bf16_f32
    union { __hip_bfloat162 h; unsigned u; } c; c.h = h; return c.u;
}
__device__ __forceinline__ bf16x4 pk4(float a0, float a1, float a2, float a3) {
    union { bf16x4 v; unsigned u[2]; } w;
    w.u[0] = cvt2(a0, a1); w.u[1] = cvt2(a2, a3);
    return w.v;
}

// R6 dataflow (A+B via LDS, K=64, M=128, 256B A-bursts, depth-1 reg prefetch)
// + R7 raw-barrier fences (no vmem drain) + nt A-loads + XCD swizzle + 4 blk/CU.
__global__ __launch_bounds__(256, 4) void bmm2_k(const float* __restrict__ a,
                                                 const float* __restrict__ b,
                                                 float* __restrict__ out) {
    // Desc-sorted static ragged tables (M=128: s/8 blocks per seq).
    const int  cumblk[9] = {0,256,448,608,736,848,944,1024,1088};
    const int  slen[8]   = {2048,1536,1280,1024,896,768,640,512};
    const long aoff[8]   = {20971520,88080384,135266304,4194304,161480704,125829120,174325760,0};
    const int  toff[8]   = {1536,3584,5888,512,7168,5120,8064,0};

    __shared__ unsigned short As[128 * 72];  // [row][k] bf16, 18.4 KB
    __shared__ unsigned short Bs[64 * 72];   // [col j][k] bf16, 9.2 KB (tot 27.7 KB)

    // Bijective XCD swizzle (1088 = 8*136).
    int bid = (blockIdx.x & 7) * 136 + (blockIdx.x >> 3);

    int i = 0;
    #pragma unroll
    for (int t = 0; t < 7; ++t) if (bid >= cumblk[t + 1]) i = t + 1;
    int rem  = bid - cumblk[i];
    int s    = slen[i];
    int nmb  = s >> 7;
    int head = rem / nmb;
    int mb   = rem - head * nmb;

    const float* A  = a + aoff[i] + (long)head * s * s + (long)mb * 128 * s;
    const float* Bp = b + (long)toff[i] * 1024 + head * 64;
    float*       Cp = out + (long)(toff[i] + mb * 128) * 1024 + head * 64;

    int tid = threadIdx.x, lane = tid & 63, wave = tid >> 6;
    int lrow = lane & 15, lgrp = lane >> 4;

    // A staging: thread -> rows {q*16 + arow}, floats kf..kf+3. One wave instr =
    // 4 consecutive rows x 256B contiguous each (the R6 pattern).
    int arow = tid >> 4;           // 0..15
    int kf   = (tid & 15) * 4;     // 0..60
    const float* Ast = A + (long)arow * s + kf;

    // B staging: thread -> tokens bk0..bk0+3, cols bj0..bj0+3.
    int bj0 = (tid & 15) * 4;
    int bk0 = (tid >> 4) * 4;
    const float* Bst = Bp + (long)bk0 * 1024 + bj0;

    f32x4 rA[8], rB[4];
    f32x4 acc[2][4] = {};
    int NT = s >> 6;

    // prologue: load tile 0 into regs (A nontemporal: read-once stream)
    #pragma unroll
    for (int q = 0; q < 8; ++q)
        rA[q] = __builtin_nontemporal_load((const f32x4*)(Ast + (long)(q * 16) * s));
    #pragma unroll
    for (int q = 0; q < 4; ++q) rB[q] = *(const f32x4*)(Bst + (long)q * 1024);

    for (int t = 0; t < NT; ++t) {
        __builtin_amdgcn_s_barrier();   // raw: readers of tile t-1 done (no vmem drain)

        // stage tile t (compiler inserts vmcnt waits for rA/rB only)
        #pragma unroll
        for (int q = 0; q < 8; ++q)
            *(bf16x4*)&As[(q * 16 + arow) * 72 + kf] = pk4(rA[q][0], rA[q][1], rA[q][2], rA[q][3]);
        #pragma unroll
        for (int e = 0; e < 4; ++e)
            *(bf16x4*)&Bs[(bj0 + e) * 72 + bk0] = pk4(rB[0][e], rB[1][e], rB[2][e], rB[3][e]);

        // issue loads(t+1) now -- they fly under compute(t), never drained at barriers
        if (t + 1 < NT) {
            long kn = (long)(t + 1) << 6;
            #pragma unroll
            for (int q = 0; q < 8; ++q)
                rA[q] = __builtin_nontemporal_load((const f32x4*)(Ast + (long)(q * 16) * s + kn));
            #pragma unroll
            for (int q = 0; q < 4; ++q) rB[q] = *(const f32x4*)(Bst + (kn + q) * 1024);
        }

        asm volatile("s_waitcnt lgkmcnt(0)" ::: "memory");   // ds_writes visible
        __builtin_amdgcn_sched_barrier(0);
        __builtin_amdgcn_s_barrier();   // tile t readable

        // compute tile t: 16 MFMA / wave
        #pragma unroll
        for (int ks = 0; ks < 2; ++ks) {
            bf16x8 af0 = *(const bf16x8*)&As[(wave * 32 + lrow) * 72 + ks * 32 + lgrp * 8];
            bf16x8 af1 = *(const bf16x8*)&As[(wave * 32 + 16 + lrow) * 72 + ks * 32 + lgrp * 8];
            bf16x8 bf[4];
            #pragma unroll
            for (int n = 0; n < 4; ++n)
                bf[n] = *(const bf16x8*)&Bs[(n * 16 + lrow) * 72 + ks * 32 + lgrp * 8];
            #pragma unroll
            for (int n = 0; n < 4; ++n) {
                acc[0][n] = __builtin_amdgcn_mfma_f32_16x16x32_bf16(af0, bf[n], acc[0][n], 0, 0, 0);
                acc[1][n] = __builtin_amdgcn_mfma_f32_16x16x32_bf16(af1, bf[n], acc[1][n], 0, 0, 0);
            }
        }
    }

    // epilogue: C/D layout col=lane&15, row=4*(lane>>4)+reg (verified R1); NT stores
    #pragma unroll
    for (int mt = 0; mt < 2; ++mt)
        #pragma unroll
        for (int n = 0; n < 4; ++n)
            #pragma unroll
            for (int r = 0; r < 4; ++r) {
                int q = wave * 32 + mt * 16 + lgrp * 4 + r;
                __builtin_nontemporal_store(acc[mt][n][r], &Cp[(long)q * 1024 + n * 16 + lrow]);
            }
}

extern "C" void kernel_launch(void* const* d_in, const int* in_sizes, int n_in,
                              void* d_out, int out_size, void* d_ws, size_t ws_size,
                              hipStream_t stream) {
    const float* a = (const float*)d_in[0];
    const float* b = (const float*)d_in[1];
    float* out = (float*)d_out;
    bmm2_k<<<1088, 256, 0, stream>>>(a, b, out);
}

// Round 13
// 173.340 us; speedup vs baseline: 1.5907x; 1.1122x over previous
//
#include <hip/hip_runtime.h>
#include <hip/hip_bf16.h>

typedef __attribute__((ext_vector_type(4))) float f32x4;
typedef __attribute__((ext_vector_type(8))) short bf16x8;
typedef __attribute__((ext_vector_type(4))) short bf16x4;

__device__ __forceinline__ unsigned cvt2(float lo, float hi) {
    float2 t; t.x = lo; t.y = hi;
    __hip_bfloat162 h = __float22bfloat162_rn(t);   // v_cvt_pk_bf16_f32
    union { __hip_bfloat162 h; unsigned u; } c; c.h = h; return c.u;
}

// M=64, K-step 64, 4 waves. Depth-2 pipeline: raw s_barrier (no vmcnt drain),
// LDS double-buffered, loads(t+2) issued in phase t -> ~2 phase-times of latency
// cover. A loads nontemporal (read-once stream; keep L2 for B).
__global__ __launch_bounds__(256, 4) void bmm2_k(const float* __restrict__ a,
                                                 const float* __restrict__ b,
                                                 float* __restrict__ out) {
    // Desc-sorted static ragged tables (M=64: 16*s/64 = s/4 blocks per seq).
    const int  cumblk[9] = {0,512,896,1216,1472,1696,1888,2048,2176};
    const int  slen[8]   = {2048,1536,1280,1024,896,768,640,512};
    const long aoff[8]   = {20971520,88080384,135266304,4194304,161480704,125829120,174325760,0};
    const int  toff[8]   = {1536,3584,5888,512,7168,5120,8064,0};

    __shared__ unsigned short As[2][64 * 72];  // [buf][row][k] bf16 (+8 pad: 2-way banks max)
    __shared__ unsigned short Bs[2][64 * 72];  // [buf][col j][k] bf16

    int bid = blockIdx.x;
    int i = 0;
    #pragma unroll
    for (int t = 0; t < 7; ++t) if (bid >= cumblk[t + 1]) i = t + 1;
    int rem  = bid - cumblk[i];
    int s    = slen[i];
    int nmb  = s >> 6;
    int head = rem / nmb;
    int mb   = rem - head * nmb;

    const float* A  = a + aoff[i] + (long)head * s * s + (long)mb * 64 * s;
    const float* Bp = b + (long)toff[i] * 1024 + head * 64;
    float*       Cp = out + (long)(toff[i] + mb * 64) * 1024 + head * 64;

    int tid = threadIdx.x, lane = tid & 63, wave = tid >> 6;
    int lrow = lane & 15, lgrp = lane >> 4;

    // A staging: thread -> rows {arow+16q}, 16B chunk kq. Wave instr = 4 rows x 256B contiguous.
    int arow = tid >> 4;          // 0..15
    int kq   = tid & 15;
    const float* Ast = A + (long)arow * s + kq * 4;

    // B staging: thread -> tokens {btok..btok+3} x cols {bcol..bcol+3} (B is L2/L3-hot)
    int bcol = (tid & 15) * 4;
    int btok = (tid >> 4) * 4;
    const float* Bst = Bp + (long)btok * 1024 + bcol;

    f32x4 lA0[4], lB0[4], lA1[4], lB1[4];   // two static register sets (depth-2)
    f32x4 acc[4] = {};

    // prologue: tiles 0 and 1 in flight
    #pragma unroll
    for (int q = 0; q < 4; ++q) {
        lA0[q] = __builtin_nontemporal_load((const f32x4*)(Ast + (long)(16 * q) * s));
        lA1[q] = __builtin_nontemporal_load((const f32x4*)(Ast + (long)(16 * q) * s + 64));
        lB0[q] = *(const f32x4*)(Bst + (long)q * 1024);
        lB1[q] = *(const f32x4*)(Bst + (long)(64 + q) * 1024);
    }

    int NTt = s >> 6;   // always even for these seqlens
    for (int t = 0; t < NTt; t += 2) {
        // ================= even phase: buf0 = tile t, prefetch t+2 =================
        __builtin_amdgcn_s_barrier();              // readers of buf0 (tile t-2) done; NO vmem drain
        #pragma unroll
        for (int q = 0; q < 4; ++q) {              // stage A (compiler waits vmcnt for lA0 only)
            union { bf16x4 v; unsigned u[2]; } w;
            w.u[0] = cvt2(lA0[q][0], lA0[q][1]);
            w.u[1] = cvt2(lA0[q][2], lA0[q][3]);
            *(bf16x4*)&As[0][(arow + 16 * q) * 72 + kq * 4] = w.v;
        }
        #pragma unroll
        for (int e = 0; e < 4; ++e) {              // stage B
            union { bf16x4 v; unsigned u[2]; } w;
            w.u[0] = cvt2(lB0[0][e], lB0[1][e]);
            w.u[1] = cvt2(lB0[2][e], lB0[3][e]);
            *(bf16x4*)&Bs[0][(bcol + e) * 72 + btok] = w.v;
        }
        {
            long kn = (t + 2 < NTt) ? ((long)(t + 2) << 6) : 0;
            #pragma unroll
            for (int q = 0; q < 4; ++q) {
                lA0[q] = __builtin_nontemporal_load((const f32x4*)(Ast + (long)(16 * q) * s + kn));
                lB0[q] = *(const f32x4*)(Bst + (kn + q) * 1024);
            }
        }
        asm volatile("s_waitcnt lgkmcnt(0)" ::: "memory");
        __builtin_amdgcn_sched_barrier(0);
        __builtin_amdgcn_s_barrier();              // buf0 visible
        #pragma unroll
        for (int ks = 0; ks < 2; ++ks) {
            bf16x8 af = *(const bf16x8*)&As[0][(wave * 16 + lrow) * 72 + ks * 32 + lgrp * 8];
            #pragma unroll
            for (int n = 0; n < 4; ++n) {
                bf16x8 bf = *(const bf16x8*)&Bs[0][(n * 16 + lrow) * 72 + ks * 32 + lgrp * 8];
                acc[n] = __builtin_amdgcn_mfma_f32_16x16x32_bf16(af, bf, acc[n], 0, 0, 0);
            }
        }
        // ================= odd phase: buf1 = tile t+1, prefetch t+3 =================
        __builtin_amdgcn_s_barrier();
        #pragma unroll
        for (int q = 0; q < 4; ++q) {
            union { bf16x4 v; unsigned u[2]; } w;
            w.u[0] = cvt2(lA1[q][0], lA1[q][1]);
            w.u[1] = cvt2(lA1[q][2], lA1[q][3]);
            *(bf16x4*)&As[1][(arow + 16 * q) * 72 + kq * 4] = w.v;
        }
        #pragma unroll
        for (int e = 0; e < 4; ++e) {
            union { bf16x4 v; unsigned u[2]; } w;
            w.u[0] = cvt2(lB1[0][e], lB1[1][e]);
            w.u[1] = cvt2(lB1[2][e], lB1[3][e]);
            *(bf16x4*)&Bs[1][(bcol + e) * 72 + btok] = w.v;
        }
        {
            long kn = (t + 3 < NTt) ? ((long)(t + 3) << 6) : 0;
            #pragma unroll
            for (int q = 0; q < 4; ++q) {
                lA1[q] = __builtin_nontemporal_load((const f32x4*)(Ast + (long)(16 * q) * s + kn));
                lB1[q] = *(const f32x4*)(Bst + (kn + q) * 1024);
            }
        }
        asm volatile("s_waitcnt lgkmcnt(0)" ::: "memory");
        __builtin_amdgcn_sched_barrier(0);
        __builtin_amdgcn_s_barrier();
        #pragma unroll
        for (int ks = 0; ks < 2; ++ks) {
            bf16x8 af = *(const bf16x8*)&As[1][(wave * 16 + lrow) * 72 + ks * 32 + lgrp * 8];
            #pragma unroll
            for (int n = 0; n < 4; ++n) {
                bf16x8 bf = *(const bf16x8*)&Bs[1][(n * 16 + lrow) * 72 + ks * 32 + lgrp * 8];
                acc[n] = __builtin_amdgcn_mfma_f32_16x16x32_bf16(af, bf, acc[n], 0, 0, 0);
            }
        }
    }

    // epilogue: C/D layout col=lane&15, row=4*(lane>>4)+reg (verified R1); NT stores
    #pragma unroll
    for (int n = 0; n < 4; ++n)
        #pragma unroll
        for (int r = 0; r < 4; ++r) {
            int q = wave * 16 + lgrp * 4 + r;
            __builtin_nontemporal_store(acc[n][r], &Cp[(long)q * 1024 + n * 16 + lrow]);
        }
}

extern "C" void kernel_launch(void* const* d_in, const int* in_sizes, int n_in,
                              void* d_out, int out_size, void* d_ws, size_t ws_size,
                              hipStream_t stream) {
    const float* a = (const float*)d_in[0];
    const float* b = (const float*)d_in[1];
    float* out = (float*)d_out;
    bmm2_k<<<2176, 256, 0, stream>>>(a, b, out);
}